// Round 1
// baseline (369.674 us; speedup 1.0000x reference)
//
#include <hip/hip_runtime.h>
#include <hip/hip_fp16.h>

#define MDIM 32
#define KDIM 8192
#define NDIM 8192
#define NT 128            // columns per workgroup (32 per wave, wave-private)
#define KC 512            // k-rows per workgroup
#define BK 64             // k-rows per tile
#define NTILES (KC / BK)  // 8
#define NSPLIT (KDIM / KC)// 16 k-splits
#define LSTRW 36          // u32 stride per kp-row in wave-private LDS (2-way banks on rd+wr)

typedef __fp16 half8 __attribute__((ext_vector_type(8)));
typedef float f32x4 __attribute__((ext_vector_type(4)));

__device__ __forceinline__ unsigned pk_u32(float a, float b) {
#if __has_builtin(__builtin_amdgcn_cvt_pkrtz)
  return __builtin_bit_cast(unsigned, __builtin_amdgcn_cvt_pkrtz(a, b));
#else
  __fp16 r2[2] = {(__fp16)a, (__fp16)b};
  return __builtin_bit_cast(unsigned, r2);
#endif
}

// rotate-left-1 key: |v| in high bits, sign in bit0. umax over keys ==
// abs-argmax (negative wins exact-magnitude ties; data has none — same
// assumption the validated butterfly kernel relied on). rotr1 recovers v.
__device__ __forceinline__ unsigned rotk(float x) {
  unsigned u = __builtin_bit_cast(unsigned, x);
  return (u << 1) | (u >> 31);
}
__device__ __forceinline__ unsigned umaxu(unsigned a, unsigned b) { return a > b ? a : b; }

// identical quantization math to the validated kernel
__device__ __forceinline__ float dq1(float v, float inv, float s) {
  float qf = fminf(fmaxf(truncf(fmaf(v, inv, 8.5f)), 0.0f), 15.0f);
  return (qf - 8.0f) * s;
}

// ---------- pre-pass: pack x[32][8192] f32 -> A-fragment-major f16 (unchanged, R4-validated) ----------
__global__ __launch_bounds__(256) void xpack_kernel(const float* __restrict__ x,
                                                    uint4* __restrict__ xpf) {
  const int T  = blockIdx.x * 256 + threadIdx.x;   // 0..32767
  const int sg = T >> 7;
  const int r  = T & 127;
  const int mt = r >> 6;
  const int L  = r & 63;
  const int m  = mt * 16 + (L & 15);
  const int k  = sg * 32 + (L >> 4) * 8;
  const float4* p = reinterpret_cast<const float4*>(x + (size_t)m * KDIM + k);
  float4 u0 = p[0], u1 = p[1];
  uint4 o;
  o.x = pk_u32(u0.x, u0.y);
  o.y = pk_u32(u0.z, u0.w);
  o.z = pk_u32(u1.x, u1.y);
  o.w = pk_u32(u1.z, u1.w);
  xpf[T] = o;
}

// ---------- fused Q4_0 fake-quant + MFMA GEMM, barrier-free wave pipelines ----------
// grid = (NDIM/NT, NSPLIT) = (64,16), block = 256 (4 independent waves).
// Each wave owns a 32-column panel: quant blocks (32 n in one k-row) never
// cross waves -> no __syncthreads anywhere. Lane = (k-pair row kp, n-half h):
// holds rows 2kp,2kp+1 x 16 cols; block absmax = 1 shfl_xor(1) per row;
// (k_even,k_odd) f16 pair for the MFMA B-layout packs in-lane via cvt_pkrtz.
__global__ __launch_bounds__(256, 4) void fused_q4_gemm(
    const uint4* __restrict__ xpf,     // packed x fragments (L2-resident, 512 KB)
    const float* __restrict__ w,       // [8192][8192]
    const float* __restrict__ bias,    // [8192]
    float* __restrict__ out)           // [32][8192]
{
  __shared__ unsigned sW[4 * 32 * LSTRW];   // 18.4 KB, wave-private [kp][n] half2 panels

  const int tid  = threadIdx.x;
  const int n0   = blockIdx.x * NT;
  const int k0   = blockIdx.y * KC;
  const int lane = tid & 63;
  const int wv   = tid >> 6;
  const int l15  = lane & 15;
  const int q    = lane >> 4;
  const int kp   = lane >> 1;        // 0..31: k-pair row within tile
  const int h    = lane & 1;         // n-half (16 cols) within the wave panel

  unsigned* __restrict__ sWv = sW + wv * (32 * LSTRW);

  f32x4 acc00 = {0.f, 0.f, 0.f, 0.f};
  f32x4 acc01 = {0.f, 0.f, 0.f, 0.f};
  f32x4 acc10 = {0.f, 0.f, 0.f, 0.f};
  f32x4 acc11 = {0.f, 0.f, 0.f, 0.f};

  const int gc0 = n0 + wv * 32 + 16 * h;              // lane's first global col
  const float* wp = w + (size_t)(k0 + 2 * kp) * NDIM + gc0;
  const uint4* ap = xpf + (size_t)(k0 >> 5) * 128 + lane;

  float4 V[8];   // rows 2kp (V[0..3]) and 2kp+1 (V[4..7]), 16 f32 each
  {
    const float4* p0 = reinterpret_cast<const float4*>(wp);
    const float4* p1 = reinterpret_cast<const float4*>(wp + NDIM);
    V[0] = p0[0]; V[1] = p0[1]; V[2] = p0[2]; V[3] = p0[3];
    V[4] = p1[0]; V[5] = p1[1]; V[6] = p1[2]; V[7] = p1[3];
  }

  for (int tt = 0; tt < NTILES; ++tt) {
    // A-fragments for this tile, issued first (L2 hits; older than the
    // V-prefetch below, so the dequant wait leaves them draining).
    uint4 xa0[2], xa1[2];
    xa0[0] = ap[0];   xa1[0] = ap[64];
    xa0[1] = ap[128]; xa1[1] = ap[192];
    ap += 256;

    // ---- dequant: lane-local key max over 2x16 values (waits on V) ----
    unsigned pe = 0u, po = 0u;
#pragma unroll
    for (int i = 0; i < 4; ++i) {
      pe = umaxu(pe, rotk(V[i].x));     pe = umaxu(pe, rotk(V[i].y));
      pe = umaxu(pe, rotk(V[i].z));     pe = umaxu(pe, rotk(V[i].w));
      po = umaxu(po, rotk(V[i + 4].x)); po = umaxu(po, rotk(V[i + 4].y));
      po = umaxu(po, rotk(V[i + 4].z)); po = umaxu(po, rotk(V[i + 4].w));
    }
    // other 16-col half of each row lives in the partner lane (lane^1)
    pe = umaxu(pe, (unsigned)__shfl_xor((int)pe, 1));
    po = umaxu(po, (unsigned)__shfl_xor((int)po, 1));
    const float bve = __builtin_bit_cast(float, (pe >> 1) | (pe << 31));
    const float bvo = __builtin_bit_cast(float, (po >> 1) | (po << 31));
    const float de = bve * -0.125f;
    const float dd = bvo * -0.125f;
    const float ie = (de == 0.0f) ? 0.0f : 1.0f / de;   // exact fp32 divide
    const float io = (dd == 0.0f) ? 0.0f : 1.0f / dd;
    const float se = __half2float(__float2half(de));    // fp16 RTNE round-trip
    const float so = __half2float(__float2half(dd));

    // quantize both rows; pack (k_even,k_odd) per column in-lane
    uint4 P[4];
#pragma unroll
    for (int i = 0; i < 4; ++i) {
      P[i].x = pk_u32(dq1(V[i].x, ie, se), dq1(V[i + 4].x, io, so));
      P[i].y = pk_u32(dq1(V[i].y, ie, se), dq1(V[i + 4].y, io, so));
      P[i].z = pk_u32(dq1(V[i].z, ie, se), dq1(V[i + 4].z, io, so));
      P[i].w = pk_u32(dq1(V[i].w, ie, se), dq1(V[i + 4].w, io, so));
    }

    // ---- prefetch next tile's rows (V regs free after P is built) ----
    if (tt + 1 < NTILES) {
      wp += (size_t)BK * NDIM;
      const float4* p0 = reinterpret_cast<const float4*>(wp);
      const float4* p1 = reinterpret_cast<const float4*>(wp + NDIM);
      V[0] = p0[0]; V[1] = p0[1]; V[2] = p0[2]; V[3] = p0[3];
      V[4] = p1[0]; V[5] = p1[1]; V[6] = p1[2]; V[7] = p1[3];
    }

    // ---- LDS write: 64B contiguous per lane, 2-way banks (free) ----
    uint4* wb = reinterpret_cast<uint4*>(sWv + kp * LSTRW + 16 * h);
    wb[0] = P[0]; wb[1] = P[1]; wb[2] = P[2]; wb[3] = P[3];

    // ---- B-frag reads + MFMA (same-wave DS pipe is in-order: no barrier) ----
#pragma unroll
    for (int ks = 0; ks < 2; ++ks) {
      const int kpb = ks * 16 + q * 4;
      uint4 b0u, b1u;
      b0u.x = sWv[(kpb + 0) * LSTRW + l15];
      b0u.y = sWv[(kpb + 1) * LSTRW + l15];
      b0u.z = sWv[(kpb + 2) * LSTRW + l15];
      b0u.w = sWv[(kpb + 3) * LSTRW + l15];
      b1u.x = sWv[(kpb + 0) * LSTRW + 16 + l15];
      b1u.y = sWv[(kpb + 1) * LSTRW + 16 + l15];
      b1u.z = sWv[(kpb + 2) * LSTRW + 16 + l15];
      b1u.w = sWv[(kpb + 3) * LSTRW + 16 + l15];
      half8 a0 = __builtin_bit_cast(half8, xa0[ks]);
      half8 a1 = __builtin_bit_cast(half8, xa1[ks]);
      half8 b0 = __builtin_bit_cast(half8, b0u);
      half8 b1 = __builtin_bit_cast(half8, b1u);
      acc00 = __builtin_amdgcn_mfma_f32_16x16x32_f16(a0, b0, acc00, 0, 0, 0);
      acc01 = __builtin_amdgcn_mfma_f32_16x16x32_f16(a0, b1, acc01, 0, 0, 0);
      acc10 = __builtin_amdgcn_mfma_f32_16x16x32_f16(a1, b0, acc10, 0, 0, 0);
      acc11 = __builtin_amdgcn_mfma_f32_16x16x32_f16(a1, b1, acc11, 0, 0, 0);
    }
  }

  // ---- epilogue: k-split partials via atomics; split 0 folds bias (validated) ----
  const int gn0 = n0 + wv * 32 + l15;
  const int gn1 = gn0 + 16;
  const float bv0 = (blockIdx.y == 0) ? bias[gn0] : 0.0f;
  const float bv1 = (blockIdx.y == 0) ? bias[gn1] : 0.0f;
#pragma unroll
  for (int r = 0; r < 4; ++r) {
    const int m0 = q * 4 + r;
    const int m1 = m0 + 16;
    atomicAdd(out + (size_t)m0 * NDIM + gn0, acc00[r] + bv0);
    atomicAdd(out + (size_t)m0 * NDIM + gn1, acc01[r] + bv1);
    atomicAdd(out + (size_t)m1 * NDIM + gn0, acc10[r] + bv0);
    atomicAdd(out + (size_t)m1 * NDIM + gn1, acc11[r] + bv1);
  }
}

extern "C" void kernel_launch(void* const* d_in, const int* in_sizes, int n_in,
                              void* d_out, int out_size, void* d_ws, size_t ws_size,
                              hipStream_t stream) {
  const float* x    = (const float*)d_in[0];   // [1,32,8192] f32
  const float* w    = (const float*)d_in[1];   // [8192,8192] f32
  const float* bias = (const float*)d_in[2];   // [8192] f32
  float* out  = (float*)d_out;                 // [1,32,8192] f32
  uint4* xpf  = (uint4*)d_ws;                  // 512 KB packed x fragments

  (void)hipMemsetAsync(out, 0, (size_t)MDIM * NDIM * sizeof(float), stream);
  xpack_kernel<<<128, 256, 0, stream>>>(x, xpf);

  dim3 grid(NDIM / NT, NSPLIT);
  fused_q4_gemm<<<grid, 256, 0, stream>>>(xpf, w, bias, out);
}

// Round 2
// 361.987 us; speedup vs baseline: 1.0212x; 1.0212x over previous
//
#include <hip/hip_runtime.h>
#include <hip/hip_fp16.h>

#define MDIM 32
#define KDIM 8192
#define NDIM 8192
#define NT 128            // columns per workgroup
#define KC 512            // k-rows per workgroup
#define BK 64             // k-rows per LDS tile
#define NTILES (KC / BK)  // 8
#define NSPLIT (KDIM / KC)// 16 k-splits
#define LSTR 130          // u32 stride per kp-row in LDS (128 + 2 pad)

typedef __fp16 half8 __attribute__((ext_vector_type(8)));
typedef float f32x4 __attribute__((ext_vector_type(4)));

__device__ __forceinline__ unsigned pk_u32(float a, float b) {
#if __has_builtin(__builtin_amdgcn_cvt_pkrtz)
  return __builtin_bit_cast(unsigned, __builtin_amdgcn_cvt_pkrtz(a, b));
#else
  __fp16 r2[2] = {(__fp16)a, (__fp16)b};
  return __builtin_bit_cast(unsigned, r2);
#endif
}

// ---------- fused Q4_0 fake-quant + MFMA GEMM (R0-validated core) ----------
// grid = (NDIM/NT, NSPLIT) = (64,16), block = 256 (4 waves).
// Change vs R0: A-fragments are packed in-kernel from raw x (L2-resident 1 MB)
// with the identical cvt_pkrtz math/indices the xpack pre-pass used.
// -> no xpack dispatch, and d_ws is completely untouched.
__global__ __launch_bounds__(256, 4) void fused_q4_gemm(
    const float* __restrict__ x,       // [32][8192] f32 (L2/L3-resident)
    const float* __restrict__ w,       // [8192][8192]
    const float* __restrict__ bias,    // [8192]
    float* __restrict__ out)           // [32][8192]
{
  __shared__ unsigned sW[32 * LSTR];   // 16.6 KB, [kp][n] half2 (k-pairs)

  const int t    = threadIdx.x;
  const int n0   = blockIdx.x * NT;
  const int k0   = blockIdx.y * KC;
  const int lane = t & 63;
  const int wv   = t >> 6;
  const int l15  = lane & 15;
  const int q    = lane >> 4;
  const int h    = lane >> 5;          // k-row parity within a load slab
  const int nl   = (lane & 31) * 4;    // first n (of 4) this lane owns in phase A

  f32x4 acc00 = {0.f, 0.f, 0.f, 0.f};
  f32x4 acc01 = {0.f, 0.f, 0.f, 0.f};
  f32x4 acc10 = {0.f, 0.f, 0.f, 0.f};
  f32x4 acc11 = {0.f, 0.f, 0.f, 0.f};

  float4 V[8];

  // prologue: fully-coalesced load of tile 0 (each instr = 1 KB contiguous)
#pragma unroll
  for (int p = 0; p < 8; ++p) {
    const int sp = p * 4 + wv;         // kp-row 0..31
    V[p] = *reinterpret_cast<const float4*>(
        w + (size_t)(k0 + 2 * sp + h) * NDIM + n0 + nl);
  }

  for (int tt = 0; tt < NTILES; ++tt) {
    const int kt = k0 + tt * BK;

    // ---- Phase A: butterfly block-scale, dequant, k-pair pack, LDS [kp][n] ----
#pragma unroll
    for (int p = 0; p < 8; ++p) {
      const int sp = p * 4 + wv;
      float4 v = V[p];
      // first-wins scan over own 4 consecutive n
      float ba = -1.0f, bv = 0.0f, a;
      a = fabsf(v.x); if (a > ba) { ba = a; bv = v.x; }
      a = fabsf(v.y); if (a > ba) { ba = a; bv = v.y; }
      a = fabsf(v.z); if (a > ba) { ba = a; bv = v.z; }
      a = fabsf(v.w); if (a > ba) { ba = a; bv = v.w; }
      // butterfly over the 8 lanes of this 32-n quant block (no exact ties in data)
#pragma unroll
      for (int msk = 1; msk <= 4; msk <<= 1) {
        float pa = __shfl_xor(ba, msk);
        float pv = __shfl_xor(bv, msk);
        if (pa > ba) { ba = pa; bv = pv; }
      }
      float d   = bv * -0.125f;
      float inv = (d == 0.0f) ? 0.0f : 1.0f / d;   // exact fp32 divide
      float s   = __half2float(__float2half(d));   // fp16 RTNE round-trip
      float q0f = fminf(fmaxf(truncf(fmaf(v.x, inv, 8.5f)), 0.0f), 15.0f);
      float q1f = fminf(fmaxf(truncf(fmaf(v.y, inv, 8.5f)), 0.0f), 15.0f);
      float q2f = fminf(fmaxf(truncf(fmaf(v.z, inv, 8.5f)), 0.0f), 15.0f);
      float q3f = fminf(fmaxf(truncf(fmaf(v.w, inv, 8.5f)), 0.0f), 15.0f);
      unsigned A = pk_u32((q0f - 8.0f) * s, (q1f - 8.0f) * s);  // (n0,n1) own k
      unsigned B = pk_u32((q2f - 8.0f) * s, (q3f - 8.0f) * s);  // (n2,n3) own k
      unsigned pA = (unsigned)__shfl_xor((int)A, 32);           // partner k
      unsigned pB = (unsigned)__shfl_xor((int)B, 32);
      unsigned lo0 = h ? pA : A, hi0 = h ? A : pA;
      unsigned lo1 = h ? pB : B, hi1 = h ? B : pB;
      unsigned D0 = (lo0 & 0xffffu) | (hi0 << 16);         // n0: (k_even, k_odd)
      unsigned D1 = (lo0 >> 16)     | (hi0 & 0xffff0000u); // n1
      unsigned D2 = (lo1 & 0xffffu) | (hi1 << 16);         // n2
      unsigned D3 = (lo1 >> 16)     | (hi1 & 0xffff0000u); // n3
      // lower half writes (n0,n1), upper half writes (n2,n3): b64, full coverage
      uint2 wr = h ? make_uint2(D2, D3) : make_uint2(D0, D1);
      *reinterpret_cast<uint2*>(&sW[sp * LSTR + nl + 2 * h]) = wr;
    }

    __syncthreads();   // A-writes visible before B-reads

    // ---- prefetch next tile's W into registers (overlaps phase B MFMA) ----
    if (tt + 1 < NTILES) {
#pragma unroll
      for (int p = 0; p < 8; ++p) {
        const int sp = p * 4 + wv;
        V[p] = *reinterpret_cast<const float4*>(
            w + (size_t)(kt + BK + 2 * sp + h) * NDIM + n0 + nl);
      }
    }

    // ---- Phase B: A from raw x packed in-register (identical cvt_pkrtz math
    //      + indices as the old xpack pre-pass), B from LDS (b32 x4, free) ----
#pragma unroll
    for (int ks = 0; ks < 2; ++ks) {
      const int kk = kt + ks * 32 + q * 8;   // 8 consecutive k per lane
      const float4* xr0 = reinterpret_cast<const float4*>(x + (size_t)l15 * KDIM + kk);
      const float4* xr1 = reinterpret_cast<const float4*>(x + (size_t)(l15 + 16) * KDIM + kk);
      float4 xu0 = xr0[0], xu1 = xr0[1];     // rows 0..15  (a0)
      float4 xv0 = xr1[0], xv1 = xr1[1];     // rows 16..31 (a1)
      uint4 a0u, a1u;
      a0u.x = pk_u32(xu0.x, xu0.y); a0u.y = pk_u32(xu0.z, xu0.w);
      a0u.z = pk_u32(xu1.x, xu1.y); a0u.w = pk_u32(xu1.z, xu1.w);
      a1u.x = pk_u32(xv0.x, xv0.y); a1u.y = pk_u32(xv0.z, xv0.w);
      a1u.z = pk_u32(xv1.x, xv1.y); a1u.w = pk_u32(xv1.z, xv1.w);
      const int kpb = ks * 16 + q * 4;
      const int nA = wv * 32 + l15;
      const int nB = nA + 16;
      uint4 b0u, b1u;
      b0u.x = sW[(kpb + 0) * LSTR + nA];
      b0u.y = sW[(kpb + 1) * LSTR + nA];
      b0u.z = sW[(kpb + 2) * LSTR + nA];
      b0u.w = sW[(kpb + 3) * LSTR + nA];
      b1u.x = sW[(kpb + 0) * LSTR + nB];
      b1u.y = sW[(kpb + 1) * LSTR + nB];
      b1u.z = sW[(kpb + 2) * LSTR + nB];
      b1u.w = sW[(kpb + 3) * LSTR + nB];
      half8 a0 = __builtin_bit_cast(half8, a0u);
      half8 a1 = __builtin_bit_cast(half8, a1u);
      half8 b0 = __builtin_bit_cast(half8, b0u);
      half8 b1 = __builtin_bit_cast(half8, b1u);
      acc00 = __builtin_amdgcn_mfma_f32_16x16x32_f16(a0, b0, acc00, 0, 0, 0);
      acc01 = __builtin_amdgcn_mfma_f32_16x16x32_f16(a0, b1, acc01, 0, 0, 0);
      acc10 = __builtin_amdgcn_mfma_f32_16x16x32_f16(a1, b0, acc10, 0, 0, 0);
      acc11 = __builtin_amdgcn_mfma_f32_16x16x32_f16(a1, b1, acc11, 0, 0, 0);
    }

    __syncthreads();   // B-reads done before next tile's A-writes
  }

  // ---- epilogue: k-split partials via atomics; split 0 folds bias (validated) ----
  const int gn0 = n0 + wv * 32 + l15;
  const int gn1 = gn0 + 16;
  const float bv0 = (blockIdx.y == 0) ? bias[gn0] : 0.0f;
  const float bv1 = (blockIdx.y == 0) ? bias[gn1] : 0.0f;
#pragma unroll
  for (int r = 0; r < 4; ++r) {
    const int m0 = q * 4 + r;
    const int m1 = m0 + 16;
    atomicAdd(out + (size_t)m0 * NDIM + gn0, acc00[r] + bv0);
    atomicAdd(out + (size_t)m0 * NDIM + gn1, acc01[r] + bv1);
    atomicAdd(out + (size_t)m1 * NDIM + gn0, acc10[r] + bv0);
    atomicAdd(out + (size_t)m1 * NDIM + gn1, acc11[r] + bv1);
  }
}

extern "C" void kernel_launch(void* const* d_in, const int* in_sizes, int n_in,
                              void* d_out, int out_size, void* d_ws, size_t ws_size,
                              hipStream_t stream) {
  const float* x    = (const float*)d_in[0];   // [1,32,8192] f32
  const float* w    = (const float*)d_in[1];   // [8192,8192] f32
  const float* bias = (const float*)d_in[2];   // [8192] f32
  float* out  = (float*)d_out;                 // [1,32,8192] f32
  (void)d_ws; (void)ws_size;                   // workspace deliberately unused

  (void)hipMemsetAsync(out, 0, (size_t)MDIM * NDIM * sizeof(float), stream);

  dim3 grid(NDIM / NT, NSPLIT);
  fused_q4_gemm<<<grid, 256, 0, stream>>>(x, w, bias, out);
}